// Round 1
// 711.828 us; speedup vs baseline: 1.3936x; 1.3936x over previous
//
#include <hip/hip_runtime.h>
#include <hip/hip_bf16.h>
#include <type_traits>

constexpr int B_ = 8, C_ = 256, P_ = 64, H_ = 64, W_ = 64, HW_ = 4096;

typedef __attribute__((ext_vector_type(8))) short short8;   // 8 bf16
typedef __attribute__((ext_vector_type(4))) short short4v;  // 4 bf16 (8 B)
typedef __attribute__((ext_vector_type(4))) float f32x4;

__device__ __forceinline__ short bfbits(float f) {
    __hip_bfloat16 h = __float2bfloat16(f);
    return *reinterpret_cast<short*>(&h);
}
__device__ __forceinline__ float bf2f(short s) {
    __hip_bfloat16 h = *reinterpret_cast<__hip_bfloat16*>(&s);
    return (float)h;
}

// ---------------------------------------------------------------------------
// Fragment-linear packed layouts (one wave-load = base + lane*16, contiguous):
//   xtP/xcP [b][tile16][kc2][lane64]x16B : chunk = x[row=tile*16+lm][p=kc*32+lq*8..+8]
//   xbP     [b][g128][ct16][lane64]x16B  : chunk = xb[c=ct*16+lm][m=g*32+lq*8..+8]
//   wbP     [tap9][cb8][cot16][lane64]x16B: chunk = w[co=cot*16+lm][ci=cb*32+lq*8..+8]
// ---------------------------------------------------------------------------

// K0: weight prep, fp32 OIHW -> fragment-linear bf16 wbP. 288 blocks.
__global__ __launch_bounds__(256) void k_prep_w(
    const float* __restrict__ w, short8* __restrict__ wbP)
{
    const int idx = blockIdx.x * 256 + threadIdx.x;      // < 9*8*16*64 = 73728
    const int lane = idx & 63, cot = (idx >> 6) & 15;
    const int cb = (idx >> 10) & 7, tap = idx >> 13;
    const int lm = lane & 15, lq = lane >> 4;
    const int co = cot * 16 + lm, ci0 = cb * 32 + lq * 8;
    short8 v;
#pragma unroll
    for (int k = 0; k < 8; ++k)
        v[k] = bfbits(w[(co * 256 + ci0 + k) * 9 + tap]);
    wbP[idx] = v;
}

// K0b: xb [B][C][HW] bf16 -> fragment-linear xbP. 4096 blocks.
// Wave handles one (b,g,ct): reads 16 c-rows x 64 B, writes 1 KB contiguous.
__global__ __launch_bounds__(256) void k_pack_xb(
    const __hip_bfloat16* __restrict__ xb, short8* __restrict__ xbP)
{
    const int tid = blockIdx.x * 256 + threadIdx.x;
    const int lane = tid & 63, wid = tid >> 6;           // wid < 8*128*16
    const int ct = wid & 15, g = (wid >> 4) & 127, b = wid >> 11;
    const int c = ct * 16 + (lane >> 2);
    const int mo = g * 32 + (lane & 3) * 8;
    const short8 v = *reinterpret_cast<const short8*>(
        &xb[((size_t)(b * 256 + c)) * HW_ + mo]);
    xbP[(size_t)wid * 64 + (lane & 3) * 16 + (lane >> 2)] = v;
}

// ---------------------------------------------------------------------------
// K1: 1x1 convs, p-quarter split (grid 16x8x8). Epilogue writes hi/lo bf16
// directly in fragment-linear xtP/xcP order.
// ---------------------------------------------------------------------------
__global__ __launch_bounds__(256) void k_conv1x1(
    const float* __restrict__ x,
    const float* __restrict__ w_top, const float* __restrict__ b_top,
    const float* __restrict__ w_cen, const float* __restrict__ b_cen,
    short8* __restrict__ xtPh, short8* __restrict__ xtPl,
    short8* __restrict__ xcPh, short8* __restrict__ xcPl)
{
    const int b = blockIdx.z;
    const int n = blockIdx.x * 256 + threadIdx.x;
    const int conv = blockIdx.y >> 2, pq = blockIdx.y & 3;
    const int p0 = pq * 16;
    const float* w    = conv ? w_cen : w_top;
    const float* bias = conv ? b_cen : b_top;
    short8* oh = conv ? xcPh : xtPh;
    short8* ol = conv ? xcPl : xtPl;

    const float* xp = x + (size_t)b * C_ * HW_ + n;
    float acc[16];
#pragma unroll
    for (int p = 0; p < 16; ++p) acc[p] = 0.f;

    for (int c = 0; c < C_; c += 4) {
        const float xv0 = xp[(size_t)(c + 0) * HW_];
        const float xv1 = xp[(size_t)(c + 1) * HW_];
        const float xv2 = xp[(size_t)(c + 2) * HW_];
        const float xv3 = xp[(size_t)(c + 3) * HW_];
#pragma unroll
        for (int p = 0; p < 16; ++p) {
            const float4 wv = *reinterpret_cast<const float4*>(&w[(p0 + p) * C_ + c]);
            float a = acc[p];
            a = fmaf(wv.x, xv0, a);
            a = fmaf(wv.y, xv1, a);
            a = fmaf(wv.z, xv2, a);
            a = fmaf(wv.w, xv3, a);
            acc[p] = a;
        }
    }
    // packed write: tile = n>>4, lm = n&15, kc = pq>>1, lq = (pq&1)*2 + jj
    const int nt = n >> 4, lmn = n & 15;
    const size_t obase = ((size_t)(b * 256 + nt) * 2 + (pq >> 1)) * 64 + lmn;
#pragma unroll
    for (int jj = 0; jj < 2; ++jj) {
        short8 vh, vl;
#pragma unroll
        for (int k = 0; k < 8; ++k) {
            const float v = acc[jj * 8 + k] + bias[p0 + jj * 8 + k];
            const short hb = bfbits(v);
            vh[k] = hb;
            vl[k] = bfbits(v - bf2f(hb));   // residual for hi/lo split
        }
        const size_t idx = obase + (size_t)(((pq & 1) * 2 + jj) * 16);
        oh[idx] = vh;
        ol[idx] = vl;
    }
}

// ---------------------------------------------------------------------------
// K2/K5: 3x3 conv as implicit GEMM, bf16 MFMA, co-half split (grid 64x2x8).
// Weights from fragment-linear wbP (contiguous 1 KB wave-loads).
// ---------------------------------------------------------------------------
template <typename OT>
__global__ __launch_bounds__(256) void k_conv3x3_mfma(
    const float* __restrict__ xin, const short8* __restrict__ wbP,
    const float* __restrict__ bias, OT* __restrict__ out)
{
    __shared__ __align__(16) __hip_bfloat16 Xs[3][66][40];
    const int b = blockIdx.z, h = blockIdx.x, cohalf = blockIdx.y;
    const int t = threadIdx.x;
    const int wave = t >> 6, lane = t & 63;
    const int lm = lane & 15, lq = lane >> 4;
    const int cobase = cohalf * 128 + wave * 32;
    const int cot0 = cohalf * 8 + wave * 2;   // co-tile index base (co/16)

    f32x4 acc[4][2];   // [n_tile][co_tile]
#pragma unroll
    for (int i = 0; i < 4; ++i)
#pragma unroll
        for (int j = 0; j < 2; ++j) acc[i][j] = f32x4{0.f, 0.f, 0.f, 0.f};

    if (t < 192) {   // zero w-halo columns once
        const int r = t >> 6, cc = t & 31, side = (t >> 5) & 1;
        Xs[r][side ? 65 : 0][cc] = __float2bfloat16(0.f);
    }

    const int ci_ld = t & 31;
    const int grp   = t >> 5;
    const float* xbase = xin + (size_t)b * C_ * HW_;

    for (int cb = 0; cb < 8; ++cb) {
        const int ci0 = cb * 32;
        __syncthreads();
#pragma unroll
        for (int it = 0; it < 6; ++it) {
            const int qr = it * 8 + grp;
            const int r = qr >> 4, wq = qr & 15;
            const int hh = h + r - 1;
            float4 v = {0.f, 0.f, 0.f, 0.f};
            if (hh >= 0 && hh < H_)
                v = *reinterpret_cast<const float4*>(
                    &xbase[(size_t)(ci0 + ci_ld) * HW_ + hh * W_ + wq * 4]);
            Xs[r][1 + wq * 4 + 0][ci_ld] = __float2bfloat16(v.x);
            Xs[r][1 + wq * 4 + 1][ci_ld] = __float2bfloat16(v.y);
            Xs[r][1 + wq * 4 + 2][ci_ld] = __float2bfloat16(v.z);
            Xs[r][1 + wq * 4 + 3][ci_ld] = __float2bfloat16(v.w);
        }
        __syncthreads();

        for (int tap = 0; tap < 9; ++tap) {
            const int dh = tap / 3;
            const int dw = tap % 3;
            short8 bf[4];
#pragma unroll
            for (int nt = 0; nt < 4; ++nt)
                bf[nt] = *reinterpret_cast<const short8*>(
                    &Xs[dh][nt * 16 + lm + dw][lq * 8]);
            const short8* wp = wbP + ((size_t)(tap * 8 + cb)) * 1024 + lane;
            short8 af[2];
            af[0] = wp[(cot0 + 0) * 64];
            af[1] = wp[(cot0 + 1) * 64];
#pragma unroll
            for (int nt = 0; nt < 4; ++nt)
#pragma unroll
                for (int ct = 0; ct < 2; ++ct)
                    acc[nt][ct] = __builtin_amdgcn_mfma_f32_16x16x32_bf16(
                        af[ct], bf[nt], acc[nt][ct], 0, 0, 0);
        }
    }

    // Epilogue [B][C][HW]. C/D: col(n)=lane&15, row(co)=lq*4+reg.
#pragma unroll
    for (int nt = 0; nt < 4; ++nt) {
        const int pos = h * W_ + nt * 16 + lm;
#pragma unroll
        for (int ct = 0; ct < 2; ++ct) {
            const int co = cobase + ct * 16 + lq * 4;
#pragma unroll
            for (int r = 0; r < 4; ++r) {
                const float v = acc[nt][ct][r] + bias[co + r];
                if constexpr (std::is_same<OT, __hip_bfloat16>::value)
                    out[((size_t)(b * C_ + co + r)) * HW_ + pos] = __float2bfloat16(v);
                else
                    out[((size_t)(b * C_ + co + r)) * HW_ + pos] = v;
            }
        }
    }
}

// ---------------------------------------------------------------------------
// K3: fused attention, all-MFMA, barrier-free, fragment-linear operand loads.
// R8: mt-loop SPLIT 4-way across blocks (global softmax => O is a pure sum
// over m; partials accumulate via atomicAdd into zeroed O). Grid 2048 blocks
// -> 16 waves/CU (reg-capped at VGPR64+ACC64=128/wave) vs 8 before.
// XCD-aware decode: all 64 n-blocks of one (b,mchunk) combo land on ONE XCD
// so its ~0.77 MB xt/xb quarter stays L2-resident (loads were L3-latency).
// ---------------------------------------------------------------------------
__global__ __launch_bounds__(256, 4) void k_attn_mfma(
    const short8* __restrict__ xtPh, const short8* __restrict__ xtPl,
    const short8* __restrict__ xcPh, const short8* __restrict__ xcPl,
    const short8* __restrict__ xbP, float* __restrict__ O,
    float* __restrict__ Z)
{
    __shared__ __align__(16) short Ps[4][16][72];   // per-wave P[n16][m64]
    __shared__ float zred[4];
    // Swizzled decode: lin%8 = XCD (dispatch round-robins XCDs); each XCD
    // owns combos xcd*4 .. xcd*4+3, each combo = (b, mchunk) with 64 n-blocks.
    const int lin = blockIdx.x;                 // 0..2047
    const int xcd = lin & 7, loc = lin >> 3;    // loc 0..255
    const int combo = xcd * 4 + (loc >> 6);     // 0..31 = b*4 + mchunk
    const int nblk = loc & 63;
    const int b = combo >> 2, mchunk = combo & 3;
    const int n0 = nblk * 64;
    const int mt0 = mchunk * 16, mt1 = mt0 + 16;

    const int t = threadIdx.x, wv = t >> 6, lane = t & 63;
    const int lm = lane & 15, lq = lane >> 4;
    const int nrow = n0 + wv * 16;

    // Hoisted S^T B-frags (xc, wave's own n-tile), contiguous loads
    short8 cB[2][2];
    {
        const size_t c8 = ((size_t)(b * 256 + (n0 >> 4) + wv) * 2) * 64 + lane;
        cB[0][0] = xcPh[c8];      cB[1][0] = xcPh[c8 + 64];
        cB[0][1] = xcPl[c8];      cB[1][1] = xcPl[c8 + 64];
    }

    f32x4 acc[16];   // O[own n-stripe][256 c] partial over this m-chunk
#pragma unroll
    for (int i = 0; i < 16; ++i) acc[i] = f32x4{0.f, 0.f, 0.f, 0.f};
    float zp = 0.f;

    for (int mt = mt0; mt < mt1; ++mt) {
        // S^T over 4 m-subtiles; A = xt (contiguous fragment-linear loads)
#pragma unroll
        for (int ms = 0; ms < 4; ++ms) {
            const size_t a8 = ((size_t)(b * 256 + mt * 4 + ms) * 2) * 64 + lane;
            const short8 aH0 = xtPh[a8];
            const short8 aH1 = xtPh[a8 + 64];
            const short8 aL0 = xtPl[a8];
            const short8 aL1 = xtPl[a8 + 64];
            f32x4 s = {0.f, 0.f, 0.f, 0.f};
            s = __builtin_amdgcn_mfma_f32_16x16x32_bf16(aH0, cB[0][0], s, 0, 0, 0);
            s = __builtin_amdgcn_mfma_f32_16x16x32_bf16(aH1, cB[1][0], s, 0, 0, 0);
            s = __builtin_amdgcn_mfma_f32_16x16x32_bf16(aH0, cB[0][1], s, 0, 0, 0);
            s = __builtin_amdgcn_mfma_f32_16x16x32_bf16(aH1, cB[1][1], s, 0, 0, 0);
            s = __builtin_amdgcn_mfma_f32_16x16x32_bf16(aL0, cB[0][0], s, 0, 0, 0);
            s = __builtin_amdgcn_mfma_f32_16x16x32_bf16(aL1, cB[1][0], s, 0, 0, 0);
            // exp + pack into own LDS region: n = lm, m = ms*16 + lq*4 + r
            const float e0 = __expf(s[0]), e1 = __expf(s[1]);
            const float e2 = __expf(s[2]), e3 = __expf(s[3]);
            zp += (e0 + e1) + (e2 + e3);
            short4v pk = { bfbits(e0), bfbits(e1), bfbits(e2), bfbits(e3) };
            *reinterpret_cast<short4v*>(&Ps[wv][lm][ms * 16 + lq * 4]) = pk;
        }
        // PV A-frags from own LDS region (same-wave lgkmcnt; no barrier)
        const short8 pa0 = *reinterpret_cast<const short8*>(&Ps[wv][lm][lq * 8]);
        const short8 pa1 = *reinterpret_cast<const short8*>(&Ps[wv][lm][32 + lq * 8]);
        // PV B-frags: contiguous fragment-linear xbP loads
        const size_t p8 = ((size_t)(b * 128 + mt * 2) * 16) * 64 + lane;
#pragma unroll
        for (int ct = 0; ct < 16; ++ct) {
            const short8 b0 = xbP[p8 + ct * 64];
            const short8 b1 = xbP[p8 + 1024 + ct * 64];
            acc[ct] = __builtin_amdgcn_mfma_f32_16x16x32_bf16(pa0, b0, acc[ct], 0, 0, 0);
            acc[ct] = __builtin_amdgcn_mfma_f32_16x16x32_bf16(pa1, b1, acc[ct], 0, 0, 0);
        }
    }

    // Z: block reduction -> one atomicAdd (sole barrier in the kernel)
#pragma unroll
    for (int o = 32; o > 0; o >>= 1) zp += __shfl_down(zp, o, 64);
    if (lane == 0) zred[wv] = zp;
    __syncthreads();
    if (t == 0) atomicAdd(&Z[b], (zred[0] + zred[1]) + (zred[2] + zred[3]));

    // O partial accumulate (atomic; 4 m-chunk blocks share each address,
    // addresses coalesced along c within each 16-lane group)
#pragma unroll
    for (int ct = 0; ct < 16; ++ct) {
        const int c = ct * 16 + lm;
#pragma unroll
        for (int r = 0; r < 4; ++r) {
            const int n = nrow + lq * 4 + r;
            atomicAdd(&O[((size_t)b * HW_ + n) * C_ + c], acc[ct][r]);
        }
    }
}

// ---------------------------------------------------------------------------
// K4: y = x + O*(1/Z[b]) (flat reinterpretation add).
// ---------------------------------------------------------------------------
__global__ __launch_bounds__(256) void k_add(
    const float* __restrict__ x, const float* __restrict__ o,
    const float* __restrict__ Z, float* __restrict__ y)
{
    const int bidx = blockIdx.x;
    const float invZ = 1.0f / Z[bidx >> 10];
    const size_t i = ((size_t)bidx * 256 + threadIdx.x) * 4;
    const float4 a = *reinterpret_cast<const float4*>(&x[i]);
    const float4 b = *reinterpret_cast<const float4*>(&o[i]);
    float4 r{fmaf(b.x, invZ, a.x), fmaf(b.y, invZ, a.y),
             fmaf(b.z, invZ, a.z), fmaf(b.w, invZ, a.w)};
    *reinterpret_cast<float4*>(&y[i]) = r;
}

extern "C" void kernel_launch(void* const* d_in, const int* in_sizes, int n_in,
                              void* d_out, int out_size, void* d_ws, size_t ws_size,
                              hipStream_t stream)
{
    const float* x   = (const float*)d_in[0];
    const float* wt  = (const float*)d_in[1];
    const float* bt  = (const float*)d_in[2];
    const float* wc  = (const float*)d_in[3];
    const float* bc  = (const float*)d_in[4];
    const float* wbo = (const float*)d_in[5];
    const float* bbo = (const float*)d_in[6];
    const float* wo  = (const float*)d_in[7];
    const float* bo  = (const float*)d_in[8];
    float* out = (float*)d_out;

    uint8_t* w8 = (uint8_t*)d_ws;
    const size_t MB = 1u << 20;
    // [0,16): xtPh/xtPl/xcPh/xcPl (4 MB each)  -> later y[0,32)
    // [16,32): xbB bf16 [B][C][HW]             -> later y upper half
    // [32,48): xbP (dead after attn)           -> wbP2 overlays after attn
    // [48,80): O   (wbP1 overlays until conv-bottom done)
    short8* xtPh = (short8*)(w8);
    short8* xtPl = (short8*)(w8 + 4 * MB);
    short8* xcPh = (short8*)(w8 + 8 * MB);
    short8* xcPl = (short8*)(w8 + 12 * MB);
    __hip_bfloat16* xbB = (__hip_bfloat16*)(w8 + 16 * MB);
    short8* xbP  = (short8*)(w8 + 32 * MB);
    float*  O    = (float*)(w8 + 48 * MB);
    short8* Wb1  = (short8*)(w8 + 48 * MB);   // inside O region (dead before attn)
    short8* Wb2  = (short8*)(w8 + 32 * MB);   // inside xbP region (dead after attn)
    float*  y    = (float*)(w8);              // [0,32) after attn
    float*  Z    = (float*)(w8 + 80 * MB);

    hipMemsetAsync(Z, 0, B_ * sizeof(float), stream);
    k_prep_w<<<dim3(288), 256, 0, stream>>>(wbo, Wb1);
    k_conv1x1<<<dim3(16, 8, 8), 256, 0, stream>>>(x, wt, bt, wc, bc,
                                                  xtPh, xtPl, xcPh, xcPl);
    k_conv3x3_mfma<__hip_bfloat16><<<dim3(64, 2, 8), 256, 0, stream>>>(x, Wb1, bbo, xbB);
    // O overlays Wb1: zero it only after conv-bottom has consumed the weights
    hipMemsetAsync(O, 0, (size_t)32 * MB, stream);
    k_pack_xb<<<dim3(4096), 256, 0, stream>>>(xbB, xbP);
    k_attn_mfma<<<dim3(2048), 256, 0, stream>>>(xtPh, xtPl, xcPh, xcPl, xbP, O, Z);
    k_prep_w<<<dim3(288), 256, 0, stream>>>(wo, Wb2);
    k_add<<<dim3(8192), 256, 0, stream>>>(x, O, Z, y);
    k_conv3x3_mfma<float><<<dim3(64, 2, 8), 256, 0, stream>>>(y, Wb2, bo, out);
}

// Round 2
// 492.409 us; speedup vs baseline: 2.0146x; 1.4456x over previous
//
#include <hip/hip_runtime.h>
#include <hip/hip_bf16.h>
#include <type_traits>

constexpr int B_ = 8, C_ = 256, P_ = 64, H_ = 64, W_ = 64, HW_ = 4096;

typedef __attribute__((ext_vector_type(8))) short short8;   // 8 bf16
typedef __attribute__((ext_vector_type(4))) short short4v;  // 4 bf16 (8 B)
typedef __attribute__((ext_vector_type(4))) float f32x4;

__device__ __forceinline__ short bfbits(float f) {
    __hip_bfloat16 h = __float2bfloat16(f);
    return *reinterpret_cast<short*>(&h);
}
__device__ __forceinline__ float bf2f(short s) {
    __hip_bfloat16 h = *reinterpret_cast<__hip_bfloat16*>(&s);
    return (float)h;
}

// async global->LDS, 16B per lane; dst must be wave-uniform base (HW adds lane*16)
#define GLL16(gsrc, ldst)                                                      \
    __builtin_amdgcn_global_load_lds(                                         \
        (const __attribute__((address_space(1))) void*)(gsrc),                \
        (__attribute__((address_space(3))) void*)(ldst), 16, 0, 0)

// ---------------------------------------------------------------------------
// Fragment-linear packed layouts (one wave-load = base + lane*16, contiguous):
//   xtP/xcP [b][tile16][kc2][lane64]x16B : chunk = x[row=tile*16+lm][p=kc*32+lq*8..+8]
//   xbP     [b][g128][ct16][lane64]x16B  : chunk = xb[c=ct*16+lm][m=g*32+lq*8..+8]
//   wbP     [tap9][cb8][cot16][lane64]x16B: chunk = w[co=cot*16+lm][ci=cb*32+lq*8..+8]
// ---------------------------------------------------------------------------

// K0: weight prep, fp32 OIHW -> fragment-linear bf16 wbP. 288 blocks.
__global__ __launch_bounds__(256) void k_prep_w(
    const float* __restrict__ w, short8* __restrict__ wbP)
{
    const int idx = blockIdx.x * 256 + threadIdx.x;      // < 9*8*16*64 = 73728
    const int lane = idx & 63, cot = (idx >> 6) & 15;
    const int cb = (idx >> 10) & 7, tap = idx >> 13;
    const int lm = lane & 15, lq = lane >> 4;
    const int co = cot * 16 + lm, ci0 = cb * 32 + lq * 8;
    short8 v;
#pragma unroll
    for (int k = 0; k < 8; ++k)
        v[k] = bfbits(w[(co * 256 + ci0 + k) * 9 + tap]);
    wbP[idx] = v;
}

// K0b: xb [B][C][HW] bf16 -> fragment-linear xbP. 4096 blocks.
__global__ __launch_bounds__(256) void k_pack_xb(
    const __hip_bfloat16* __restrict__ xb, short8* __restrict__ xbP)
{
    const int tid = blockIdx.x * 256 + threadIdx.x;
    const int lane = tid & 63, wid = tid >> 6;           // wid < 8*128*16
    const int ct = wid & 15, g = (wid >> 4) & 127, b = wid >> 11;
    const int c = ct * 16 + (lane >> 2);
    const int mo = g * 32 + (lane & 3) * 8;
    const short8 v = *reinterpret_cast<const short8*>(
        &xb[((size_t)(b * 256 + c)) * HW_ + mo]);
    xbP[(size_t)wid * 64 + (lane & 3) * 16 + (lane >> 2)] = v;
}

// ---------------------------------------------------------------------------
// K1: 1x1 convs, p-quarter split (grid 16x8x8). Epilogue writes hi/lo bf16
// directly in fragment-linear xtP/xcP order.
// ---------------------------------------------------------------------------
__global__ __launch_bounds__(256) void k_conv1x1(
    const float* __restrict__ x,
    const float* __restrict__ w_top, const float* __restrict__ b_top,
    const float* __restrict__ w_cen, const float* __restrict__ b_cen,
    short8* __restrict__ xtPh, short8* __restrict__ xtPl,
    short8* __restrict__ xcPh, short8* __restrict__ xcPl)
{
    const int b = blockIdx.z;
    const int n = blockIdx.x * 256 + threadIdx.x;
    const int conv = blockIdx.y >> 2, pq = blockIdx.y & 3;
    const int p0 = pq * 16;
    const float* w    = conv ? w_cen : w_top;
    const float* bias = conv ? b_cen : b_top;
    short8* oh = conv ? xcPh : xtPh;
    short8* ol = conv ? xcPl : xtPl;

    const float* xp = x + (size_t)b * C_ * HW_ + n;
    float acc[16];
#pragma unroll
    for (int p = 0; p < 16; ++p) acc[p] = 0.f;

    for (int c = 0; c < C_; c += 4) {
        const float xv0 = xp[(size_t)(c + 0) * HW_];
        const float xv1 = xp[(size_t)(c + 1) * HW_];
        const float xv2 = xp[(size_t)(c + 2) * HW_];
        const float xv3 = xp[(size_t)(c + 3) * HW_];
#pragma unroll
        for (int p = 0; p < 16; ++p) {
            const float4 wv = *reinterpret_cast<const float4*>(&w[(p0 + p) * C_ + c]);
            float a = acc[p];
            a = fmaf(wv.x, xv0, a);
            a = fmaf(wv.y, xv1, a);
            a = fmaf(wv.z, xv2, a);
            a = fmaf(wv.w, xv3, a);
            acc[p] = a;
        }
    }
    const int nt = n >> 4, lmn = n & 15;
    const size_t obase = ((size_t)(b * 256 + nt) * 2 + (pq >> 1)) * 64 + lmn;
#pragma unroll
    for (int jj = 0; jj < 2; ++jj) {
        short8 vh, vl;
#pragma unroll
        for (int k = 0; k < 8; ++k) {
            const float v = acc[jj * 8 + k] + bias[p0 + jj * 8 + k];
            const short hb = bfbits(v);
            vh[k] = hb;
            vl[k] = bfbits(v - bf2f(hb));   // residual for hi/lo split
        }
        const size_t idx = obase + (size_t)(((pq & 1) * 2 + jj) * 16);
        oh[idx] = vh;
        ol[idx] = vl;
    }
}

// ---------------------------------------------------------------------------
// K2/K5: 3x3 conv as implicit GEMM, bf16 MFMA, co-half split (grid 64x2x8).
// ---------------------------------------------------------------------------
template <typename OT>
__global__ __launch_bounds__(256) void k_conv3x3_mfma(
    const float* __restrict__ xin, const short8* __restrict__ wbP,
    const float* __restrict__ bias, OT* __restrict__ out)
{
    __shared__ __align__(16) __hip_bfloat16 Xs[3][66][40];
    const int b = blockIdx.z, h = blockIdx.x, cohalf = blockIdx.y;
    const int t = threadIdx.x;
    const int wave = t >> 6, lane = t & 63;
    const int lm = lane & 15, lq = lane >> 4;
    const int cobase = cohalf * 128 + wave * 32;
    const int cot0 = cohalf * 8 + wave * 2;   // co-tile index base (co/16)

    f32x4 acc[4][2];   // [n_tile][co_tile]
#pragma unroll
    for (int i = 0; i < 4; ++i)
#pragma unroll
        for (int j = 0; j < 2; ++j) acc[i][j] = f32x4{0.f, 0.f, 0.f, 0.f};

    if (t < 192) {   // zero w-halo columns once
        const int r = t >> 6, cc = t & 31, side = (t >> 5) & 1;
        Xs[r][side ? 65 : 0][cc] = __float2bfloat16(0.f);
    }

    const int ci_ld = t & 31;
    const int grp   = t >> 5;
    const float* xbase = xin + (size_t)b * C_ * HW_;

    for (int cb = 0; cb < 8; ++cb) {
        const int ci0 = cb * 32;
        __syncthreads();
#pragma unroll
        for (int it = 0; it < 6; ++it) {
            const int qr = it * 8 + grp;
            const int r = qr >> 4, wq = qr & 15;
            const int hh = h + r - 1;
            float4 v = {0.f, 0.f, 0.f, 0.f};
            if (hh >= 0 && hh < H_)
                v = *reinterpret_cast<const float4*>(
                    &xbase[(size_t)(ci0 + ci_ld) * HW_ + hh * W_ + wq * 4]);
            Xs[r][1 + wq * 4 + 0][ci_ld] = __float2bfloat16(v.x);
            Xs[r][1 + wq * 4 + 1][ci_ld] = __float2bfloat16(v.y);
            Xs[r][1 + wq * 4 + 2][ci_ld] = __float2bfloat16(v.z);
            Xs[r][1 + wq * 4 + 3][ci_ld] = __float2bfloat16(v.w);
        }
        __syncthreads();

        for (int tap = 0; tap < 9; ++tap) {
            const int dh = tap / 3;
            const int dw = tap % 3;
            short8 bf[4];
#pragma unroll
            for (int nt = 0; nt < 4; ++nt)
                bf[nt] = *reinterpret_cast<const short8*>(
                    &Xs[dh][nt * 16 + lm + dw][lq * 8]);
            const short8* wp = wbP + ((size_t)(tap * 8 + cb)) * 1024 + lane;
            short8 af[2];
            af[0] = wp[(cot0 + 0) * 64];
            af[1] = wp[(cot0 + 1) * 64];
#pragma unroll
            for (int nt = 0; nt < 4; ++nt)
#pragma unroll
                for (int ct = 0; ct < 2; ++ct)
                    acc[nt][ct] = __builtin_amdgcn_mfma_f32_16x16x32_bf16(
                        af[ct], bf[nt], acc[nt][ct], 0, 0, 0);
        }
    }

#pragma unroll
    for (int nt = 0; nt < 4; ++nt) {
        const int pos = h * W_ + nt * 16 + lm;
#pragma unroll
        for (int ct = 0; ct < 2; ++ct) {
            const int co = cobase + ct * 16 + lq * 4;
#pragma unroll
            for (int r = 0; r < 4; ++r) {
                const float v = acc[nt][ct][r] + bias[co + r];
                if constexpr (std::is_same<OT, __hip_bfloat16>::value)
                    out[((size_t)(b * C_ + co + r)) * HW_ + pos] = __float2bfloat16(v);
                else
                    out[((size_t)(b * C_ + co + r)) * HW_ + pos] = v;
            }
        }
    }
}

// ---------------------------------------------------------------------------
// K3: fused attention. R9: 8-wave (512t) blocks, LDS-staged xt/xb shared by
// all waves (global_load_lds w16, fragment-linear = exact DMA order), PV
// phase re-split by (n-quad x c-quarter) so waves don't re-read all 256 c.
// Global reads drop 6.3GB -> 0.79GB (was L3-BW-bound at ~14TB/s = 441us).
// 3 raw barriers/mt with counted vmcnt(4): xb loads stay in flight under S^T.
// Grid 1024 = 8 XCD * (4 mchunk * 32 nblk); b == XCD. 2 blocks/CU (67.6KB LDS).
// ---------------------------------------------------------------------------
__global__ __launch_bounds__(512, 4) void k_attn_mfma(
    const short8* __restrict__ xtPh, const short8* __restrict__ xtPl,
    const short8* __restrict__ xcPh, const short8* __restrict__ xcPl,
    const short8* __restrict__ xbP, float* __restrict__ O,
    float* __restrict__ Z)
{
    extern __shared__ __align__(16) char smem[];
    short8* XTs = (short8*)smem;                      // 1024 chunks-of-lane: 16KB
    short8* XBs = (short8*)(smem + 16384);            // 2048: 32KB
    short8* Ps8 = (short8*)(smem + 49152);            // [8 tiles][16 n][72 m] shorts
    short4v* Ps4 = (short4v*)(smem + 49152);
    float* zred = (float*)(smem + 67584);

    const int lin = blockIdx.x;                 // 0..1023
    const int xcd = lin & 7, j = lin >> 3;      // j 0..127
    const int b = xcd, mchunk = j >> 5, nblk = j & 31;
    const int n0 = nblk * 128;
    const int mt0 = mchunk * 16, mt1 = mt0 + 16;

    const int t = threadIdx.x, wv = t >> 6, lane = t & 63;
    const int lm = lane & 15, lq = lane >> 4;
    const int nq = wv >> 2, cq = wv & 3;        // PV split: n-quad x c-quarter

    // Hoisted S^T B-frags (xc, wave's own n-tile = nblk*8 + wv)
    short8 cB[2][2];
    {
        const size_t c8 = ((size_t)(b * 256 + nblk * 8 + wv) * 2) * 64 + lane;
        cB[0][0] = xcPh[c8];      cB[1][0] = xcPh[c8 + 64];
        cB[0][1] = xcPl[c8];      cB[1][1] = xcPl[c8 + 64];
    }

    f32x4 acc[4][4];   // O partial [n-subtile within quad][c-tile within quarter]
#pragma unroll
    for (int i = 0; i < 4; ++i)
#pragma unroll
        for (int jj = 0; jj < 4; ++jj) acc[i][jj] = f32x4{0.f, 0.f, 0.f, 0.f};
    float zp = 0.f;

    for (int mt = mt0; mt < mt1; ++mt) {
        // ---- barrier A: previous iteration's LDS reads complete ----
        __builtin_amdgcn_s_barrier();
        __builtin_amdgcn_sched_barrier(0);
        // ---- stage: 2 xt chunks then 4 xb chunks per wave ----
        {
            const size_t abase0 = ((size_t)(b * 512 + mt * 8)) * 64;
#pragma unroll
            for (int k = 0; k < 2; ++k) {
                const int c = wv * 2 + k;              // 0..15
                const int ms = c >> 2, part = c & 3;
                const short8* src = (part < 2 ? xtPh : xtPl)
                                    + abase0 + ms * 128 + (part & 1) * 64 + lane;
                GLL16(src, XTs + c * 64);
            }
            const size_t p8 = ((size_t)(b * 2048 + mt * 32)) * 64;
#pragma unroll
            for (int k = 0; k < 4; ++k) {
                const int e = k * 512 + wv * 64;       // element idx in 2048
                GLL16(xbP + p8 + e + lane, XBs + e);
            }
        }
        asm volatile("s_waitcnt vmcnt(4)" ::: "memory");   // own xt done; xb in flight
        __builtin_amdgcn_sched_barrier(0);
        __builtin_amdgcn_s_barrier();                       // A2: all xt staged
        __builtin_amdgcn_sched_barrier(0);

        // ---- S^T: wave's own 16-n tile over this mt's 64 m (from LDS XT) ----
#pragma unroll
        for (int ms = 0; ms < 4; ++ms) {
            const short8 aH0 = XTs[(ms * 4 + 0) * 64 + lane];
            const short8 aH1 = XTs[(ms * 4 + 1) * 64 + lane];
            const short8 aL0 = XTs[(ms * 4 + 2) * 64 + lane];
            const short8 aL1 = XTs[(ms * 4 + 3) * 64 + lane];
            f32x4 s = {0.f, 0.f, 0.f, 0.f};
            __builtin_amdgcn_s_setprio(1);
            s = __builtin_amdgcn_mfma_f32_16x16x32_bf16(aH0, cB[0][0], s, 0, 0, 0);
            s = __builtin_amdgcn_mfma_f32_16x16x32_bf16(aH1, cB[1][0], s, 0, 0, 0);
            s = __builtin_amdgcn_mfma_f32_16x16x32_bf16(aH0, cB[0][1], s, 0, 0, 0);
            s = __builtin_amdgcn_mfma_f32_16x16x32_bf16(aH1, cB[1][1], s, 0, 0, 0);
            s = __builtin_amdgcn_mfma_f32_16x16x32_bf16(aL0, cB[0][0], s, 0, 0, 0);
            s = __builtin_amdgcn_mfma_f32_16x16x32_bf16(aL1, cB[1][0], s, 0, 0, 0);
            __builtin_amdgcn_s_setprio(0);
            const float e0 = __expf(s[0]), e1 = __expf(s[1]);
            const float e2 = __expf(s[2]), e3 = __expf(s[3]);
            zp += (e0 + e1) + (e2 + e3);
            short4v pk = { bfbits(e0), bfbits(e1), bfbits(e2), bfbits(e3) };
            Ps4[wv * 288 + lm * 18 + ms * 4 + lq] = pk;   // [wv][n=lm][m=ms*16+lq*4]
        }
        asm volatile("s_waitcnt vmcnt(0) lgkmcnt(0)" ::: "memory");  // xb + Ps done
        __builtin_amdgcn_sched_barrier(0);
        __builtin_amdgcn_s_barrier();                       // B: Ps + XB visible
        __builtin_amdgcn_sched_barrier(0);

        // ---- PV: wave = (nq, cq) -> 64 n x 64 c, reading cross-wave Ps ----
#pragma unroll
        for (int h = 0; h < 2; ++h) {
            short8 b0[2], b1[2];
#pragma unroll
            for (int q = 0; q < 2; ++q) {
                const int ct = cq * 4 + h * 2 + q;
                b0[q] = XBs[ct * 64 + lane];
                b1[q] = XBs[1024 + ct * 64 + lane];
            }
#pragma unroll
            for (int nt2 = 0; nt2 < 4; ++nt2) {
                const int tile = nq * 4 + nt2;
                const short8 pa0 = Ps8[tile * 144 + lm * 9 + lq];
                const short8 pa1 = Ps8[tile * 144 + lm * 9 + 4 + lq];
                __builtin_amdgcn_s_setprio(1);
#pragma unroll
                for (int q = 0; q < 2; ++q) {
                    acc[nt2][h * 2 + q] = __builtin_amdgcn_mfma_f32_16x16x32_bf16(
                        pa0, b0[q], acc[nt2][h * 2 + q], 0, 0, 0);
                    acc[nt2][h * 2 + q] = __builtin_amdgcn_mfma_f32_16x16x32_bf16(
                        pa1, b1[q], acc[nt2][h * 2 + q], 0, 0, 0);
                }
                __builtin_amdgcn_s_setprio(0);
            }
        }
    }

    // Z: block reduction -> one atomicAdd
#pragma unroll
    for (int o = 32; o > 0; o >>= 1) zp += __shfl_down(zp, o, 64);
    if (lane == 0) zred[wv] = zp;
    __syncthreads();
    if (t == 0) {
        float zs = 0.f;
#pragma unroll
        for (int wvi = 0; wvi < 8; ++wvi) zs += zred[wvi];
        atomicAdd(&Z[b], zs);
    }

    // O partial accumulate (atomic; 4 m-chunk blocks share each address)
#pragma unroll
    for (int nt2 = 0; nt2 < 4; ++nt2) {
#pragma unroll
        for (int ct2 = 0; ct2 < 4; ++ct2) {
            const int c = cq * 64 + ct2 * 16 + lm;
#pragma unroll
            for (int r = 0; r < 4; ++r) {
                const int n = n0 + (nq * 4 + nt2) * 16 + lq * 4 + r;
                atomicAdd(&O[((size_t)b * HW_ + n) * C_ + c], acc[nt2][ct2][r]);
            }
        }
    }
}

// ---------------------------------------------------------------------------
// K4: y = x + O*(1/Z[b]) (flat reinterpretation add).
// ---------------------------------------------------------------------------
__global__ __launch_bounds__(256) void k_add(
    const float* __restrict__ x, const float* __restrict__ o,
    const float* __restrict__ Z, float* __restrict__ y)
{
    const int bidx = blockIdx.x;
    const float invZ = 1.0f / Z[bidx >> 10];
    const size_t i = ((size_t)bidx * 256 + threadIdx.x) * 4;
    const float4 a = *reinterpret_cast<const float4*>(&x[i]);
    const float4 b = *reinterpret_cast<const float4*>(&o[i]);
    float4 r{fmaf(b.x, invZ, a.x), fmaf(b.y, invZ, a.y),
             fmaf(b.z, invZ, a.z), fmaf(b.w, invZ, a.w)};
    *reinterpret_cast<float4*>(&y[i]) = r;
}

extern "C" void kernel_launch(void* const* d_in, const int* in_sizes, int n_in,
                              void* d_out, int out_size, void* d_ws, size_t ws_size,
                              hipStream_t stream)
{
    const float* x   = (const float*)d_in[0];
    const float* wt  = (const float*)d_in[1];
    const float* bt  = (const float*)d_in[2];
    const float* wc  = (const float*)d_in[3];
    const float* bc  = (const float*)d_in[4];
    const float* wbo = (const float*)d_in[5];
    const float* bbo = (const float*)d_in[6];
    const float* wo  = (const float*)d_in[7];
    const float* bo  = (const float*)d_in[8];
    float* out = (float*)d_out;

    uint8_t* w8 = (uint8_t*)d_ws;
    const size_t MB = 1u << 20;
    short8* xtPh = (short8*)(w8);
    short8* xtPl = (short8*)(w8 + 4 * MB);
    short8* xcPh = (short8*)(w8 + 8 * MB);
    short8* xcPl = (short8*)(w8 + 12 * MB);
    __hip_bfloat16* xbB = (__hip_bfloat16*)(w8 + 16 * MB);
    short8* xbP  = (short8*)(w8 + 32 * MB);
    float*  O    = (float*)(w8 + 48 * MB);
    short8* Wb1  = (short8*)(w8 + 48 * MB);   // inside O region (dead before attn)
    short8* Wb2  = (short8*)(w8 + 32 * MB);   // inside xbP region (dead after attn)
    float*  y    = (float*)(w8);              // [0,32) after attn
    float*  Z    = (float*)(w8 + 80 * MB);

    hipMemsetAsync(Z, 0, B_ * sizeof(float), stream);
    k_prep_w<<<dim3(288), 256, 0, stream>>>(wbo, Wb1);
    k_conv1x1<<<dim3(16, 8, 8), 256, 0, stream>>>(x, wt, bt, wc, bc,
                                                  xtPh, xtPl, xcPh, xcPl);
    k_conv3x3_mfma<__hip_bfloat16><<<dim3(64, 2, 8), 256, 0, stream>>>(x, Wb1, bbo, xbB);
    // O overlays Wb1: zero it only after conv-bottom has consumed the weights
    hipMemsetAsync(O, 0, (size_t)32 * MB, stream);
    k_pack_xb<<<dim3(4096), 256, 0, stream>>>(xbB, xbP);
    k_attn_mfma<<<dim3(1024), dim3(512), 67616, stream>>>(xtPh, xtPl, xcPh, xcPl,
                                                          xbP, O, Z);
    k_prep_w<<<dim3(288), 256, 0, stream>>>(wo, Wb2);
    k_add<<<dim3(8192), 256, 0, stream>>>(x, O, Z, y);
    k_conv3x3_mfma<float><<<dim3(64, 2, 8), 256, 0, stream>>>(y, Wb2, bo, out);
}

// Round 3
// 399.940 us; speedup vs baseline: 2.4804x; 1.2312x over previous
//
#include <hip/hip_runtime.h>
#include <hip/hip_bf16.h>
#include <type_traits>

constexpr int B_ = 8, C_ = 256, P_ = 64, H_ = 64, W_ = 64, HW_ = 4096;

typedef __attribute__((ext_vector_type(8))) short short8;   // 8 bf16
typedef __attribute__((ext_vector_type(4))) short short4v;  // 4 bf16 (8 B)
typedef __attribute__((ext_vector_type(4))) float f32x4;

__device__ __forceinline__ short bfbits(float f) {
    __hip_bfloat16 h = __float2bfloat16(f);
    return *reinterpret_cast<short*>(&h);
}
__device__ __forceinline__ float bf2f(short s) {
    __hip_bfloat16 h = *reinterpret_cast<__hip_bfloat16*>(&s);
    return (float)h;
}

// async global->LDS, 16B per lane; dst must be wave-uniform base (HW adds lane*16)
#define GLL16(gsrc, ldst)                                                      \
    __builtin_amdgcn_global_load_lds(                                         \
        (const __attribute__((address_space(1))) void*)(gsrc),                \
        (__attribute__((address_space(3))) void*)(ldst), 16, 0, 0)

// ---------------------------------------------------------------------------
// Fragment-linear packed layouts (one wave-load = base + lane*16, contiguous):
//   xtP/xcP [b][tile16][kc2][lane64]x16B : chunk = x[row=tile*16+lm][p=kc*32+lq*8..+8]
//   xbP     [b][g128][ct16][lane64]x16B  : chunk = xb[c=ct*16+lm][m=g*32+lq*8..+8]
//   wbP     [tap9][cb8][cot16][lane64]x16B: chunk = w[co=cot*16+lm][ci=cb*32+lq*8..+8]
// ---------------------------------------------------------------------------

// K0: weight prep, fp32 OIHW -> fragment-linear bf16 wbP. 288 blocks.
__global__ __launch_bounds__(256) void k_prep_w(
    const float* __restrict__ w, short8* __restrict__ wbP)
{
    const int idx = blockIdx.x * 256 + threadIdx.x;      // < 9*8*16*64 = 73728
    const int lane = idx & 63, cot = (idx >> 6) & 15;
    const int cb = (idx >> 10) & 7, tap = idx >> 13;
    const int lm = lane & 15, lq = lane >> 4;
    const int co = cot * 16 + lm, ci0 = cb * 32 + lq * 8;
    short8 v;
#pragma unroll
    for (int k = 0; k < 8; ++k)
        v[k] = bfbits(w[(co * 256 + ci0 + k) * 9 + tap]);
    wbP[idx] = v;
}

// K0b: xb [B][C][HW] bf16 -> fragment-linear xbP. 4096 blocks.
__global__ __launch_bounds__(256) void k_pack_xb(
    const __hip_bfloat16* __restrict__ xb, short8* __restrict__ xbP)
{
    const int tid = blockIdx.x * 256 + threadIdx.x;
    const int lane = tid & 63, wid = tid >> 6;           // wid < 8*128*16
    const int ct = wid & 15, g = (wid >> 4) & 127, b = wid >> 11;
    const int c = ct * 16 + (lane >> 2);
    const int mo = g * 32 + (lane & 3) * 8;
    const short8 v = *reinterpret_cast<const short8*>(
        &xb[((size_t)(b * 256 + c)) * HW_ + mo]);
    xbP[(size_t)wid * 64 + (lane & 3) * 16 + (lane >> 2)] = v;
}

// ---------------------------------------------------------------------------
// K1: 1x1 convs, p-quarter split (grid 16x8x8). Epilogue writes hi/lo bf16
// directly in fragment-linear xtP/xcP order.
// ---------------------------------------------------------------------------
__global__ __launch_bounds__(256) void k_conv1x1(
    const float* __restrict__ x,
    const float* __restrict__ w_top, const float* __restrict__ b_top,
    const float* __restrict__ w_cen, const float* __restrict__ b_cen,
    short8* __restrict__ xtPh, short8* __restrict__ xtPl,
    short8* __restrict__ xcPh, short8* __restrict__ xcPl)
{
    const int b = blockIdx.z;
    const int n = blockIdx.x * 256 + threadIdx.x;
    const int conv = blockIdx.y >> 2, pq = blockIdx.y & 3;
    const int p0 = pq * 16;
    const float* w    = conv ? w_cen : w_top;
    const float* bias = conv ? b_cen : b_top;
    short8* oh = conv ? xcPh : xtPh;
    short8* ol = conv ? xcPl : xtPl;

    const float* xp = x + (size_t)b * C_ * HW_ + n;
    float acc[16];
#pragma unroll
    for (int p = 0; p < 16; ++p) acc[p] = 0.f;

    for (int c = 0; c < C_; c += 4) {
        const float xv0 = xp[(size_t)(c + 0) * HW_];
        const float xv1 = xp[(size_t)(c + 1) * HW_];
        const float xv2 = xp[(size_t)(c + 2) * HW_];
        const float xv3 = xp[(size_t)(c + 3) * HW_];
#pragma unroll
        for (int p = 0; p < 16; ++p) {
            const float4 wv = *reinterpret_cast<const float4*>(&w[(p0 + p) * C_ + c]);
            float a = acc[p];
            a = fmaf(wv.x, xv0, a);
            a = fmaf(wv.y, xv1, a);
            a = fmaf(wv.z, xv2, a);
            a = fmaf(wv.w, xv3, a);
            acc[p] = a;
        }
    }
    const int nt = n >> 4, lmn = n & 15;
    const size_t obase = ((size_t)(b * 256 + nt) * 2 + (pq >> 1)) * 64 + lmn;
#pragma unroll
    for (int jj = 0; jj < 2; ++jj) {
        short8 vh, vl;
#pragma unroll
        for (int k = 0; k < 8; ++k) {
            const float v = acc[jj * 8 + k] + bias[p0 + jj * 8 + k];
            const short hb = bfbits(v);
            vh[k] = hb;
            vl[k] = bfbits(v - bf2f(hb));   // residual for hi/lo split
        }
        const size_t idx = obase + (size_t)(((pq & 1) * 2 + jj) * 16);
        oh[idx] = vh;
        ol[idx] = vl;
    }
}

// ---------------------------------------------------------------------------
// K2/K5: 3x3 conv as implicit GEMM, bf16 MFMA, co-half split (grid 64x2x8).
// ---------------------------------------------------------------------------
template <typename OT>
__global__ __launch_bounds__(256) void k_conv3x3_mfma(
    const float* __restrict__ xin, const short8* __restrict__ wbP,
    const float* __restrict__ bias, OT* __restrict__ out)
{
    __shared__ __align__(16) __hip_bfloat16 Xs[3][66][40];
    const int b = blockIdx.z, h = blockIdx.x, cohalf = blockIdx.y;
    const int t = threadIdx.x;
    const int wave = t >> 6, lane = t & 63;
    const int lm = lane & 15, lq = lane >> 4;
    const int cobase = cohalf * 128 + wave * 32;
    const int cot0 = cohalf * 8 + wave * 2;   // co-tile index base (co/16)

    f32x4 acc[4][2];   // [n_tile][co_tile]
#pragma unroll
    for (int i = 0; i < 4; ++i)
#pragma unroll
        for (int j = 0; j < 2; ++j) acc[i][j] = f32x4{0.f, 0.f, 0.f, 0.f};

    if (t < 192) {   // zero w-halo columns once
        const int r = t >> 6, cc = t & 31, side = (t >> 5) & 1;
        Xs[r][side ? 65 : 0][cc] = __float2bfloat16(0.f);
    }

    const int ci_ld = t & 31;
    const int grp   = t >> 5;
    const float* xbase = xin + (size_t)b * C_ * HW_;

    for (int cb = 0; cb < 8; ++cb) {
        const int ci0 = cb * 32;
        __syncthreads();
#pragma unroll
        for (int it = 0; it < 6; ++it) {
            const int qr = it * 8 + grp;
            const int r = qr >> 4, wq = qr & 15;
            const int hh = h + r - 1;
            float4 v = {0.f, 0.f, 0.f, 0.f};
            if (hh >= 0 && hh < H_)
                v = *reinterpret_cast<const float4*>(
                    &xbase[(size_t)(ci0 + ci_ld) * HW_ + hh * W_ + wq * 4]);
            Xs[r][1 + wq * 4 + 0][ci_ld] = __float2bfloat16(v.x);
            Xs[r][1 + wq * 4 + 1][ci_ld] = __float2bfloat16(v.y);
            Xs[r][1 + wq * 4 + 2][ci_ld] = __float2bfloat16(v.z);
            Xs[r][1 + wq * 4 + 3][ci_ld] = __float2bfloat16(v.w);
        }
        __syncthreads();

        for (int tap = 0; tap < 9; ++tap) {
            const int dh = tap / 3;
            const int dw = tap % 3;
            short8 bf[4];
#pragma unroll
            for (int nt = 0; nt < 4; ++nt)
                bf[nt] = *reinterpret_cast<const short8*>(
                    &Xs[dh][nt * 16 + lm + dw][lq * 8]);
            const short8* wp = wbP + ((size_t)(tap * 8 + cb)) * 1024 + lane;
            short8 af[2];
            af[0] = wp[(cot0 + 0) * 64];
            af[1] = wp[(cot0 + 1) * 64];
#pragma unroll
            for (int nt = 0; nt < 4; ++nt)
#pragma unroll
                for (int ct = 0; ct < 2; ++ct)
                    acc[nt][ct] = __builtin_amdgcn_mfma_f32_16x16x32_bf16(
                        af[ct], bf[nt], acc[nt][ct], 0, 0, 0);
        }
    }

#pragma unroll
    for (int nt = 0; nt < 4; ++nt) {
        const int pos = h * W_ + nt * 16 + lm;
#pragma unroll
        for (int ct = 0; ct < 2; ++ct) {
            const int co = cobase + ct * 16 + lq * 4;
#pragma unroll
            for (int r = 0; r < 4; ++r) {
                const float v = acc[nt][ct][r] + bias[co + r];
                if constexpr (std::is_same<OT, __hip_bfloat16>::value)
                    out[((size_t)(b * C_ + co + r)) * HW_ + pos] = __float2bfloat16(v);
                else
                    out[((size_t)(b * C_ + co + r)) * HW_ + pos] = v;
            }
        }
    }
}

// ---------------------------------------------------------------------------
// K3: fused attention. R10: one block per (b, 128-n stripe): grid 256 = 1/CU,
// all 64 mt per block -> direct O stores (no atomics, no memset). Double-
// buffered XT/XB staging via global_load_lds with COUNTED waits (vmcnt(4)
// before S^T: xt landed / xb in flight; vmcnt(6) before PV: next tile's 6
// loads stay in flight across barriers - never vmcnt(0) in the loop).
// S^T split 2m x 4n across waves (halves XT LDS reads); Ps stored fragment-
// linear [T][mhalf][lane]x16B so PV pa reads are the conflict-free lane*16
// pattern. 2 barriers/iter. LDS 114.7 KB, 1 block/CU, 8 waves. b == XCD.
// ---------------------------------------------------------------------------
__global__ __launch_bounds__(512, 2) void k_attn_mfma(
    const short8* __restrict__ xtPh, const short8* __restrict__ xtPl,
    const short8* __restrict__ xcPh, const short8* __restrict__ xcPl,
    const short8* __restrict__ xbP, float* __restrict__ O,
    float* __restrict__ Z)
{
    extern __shared__ __align__(16) char smem[];
    short8* XTs = (short8*)smem;                    // [2][1024]  (2 x 16 KB)
    short8* XBs = (short8*)(smem + 32768);          // [2][2048]  (2 x 32 KB)
    short8* Ps8 = (short8*)(smem + 98304);          // [8 T][2 mh][64]  16 KB
    short4v* Ps4 = (short4v*)(smem + 98304);
    float* zred = (float*)(smem + 114688);

    const int lin = blockIdx.x;                 // 0..255
    const int b = lin & 7, nblk = lin >> 3;     // b == XCD (round-robin dispatch)
    const int n0 = nblk * 128;

    const int t = threadIdx.x, wv = t >> 6, lane = t & 63;
    const int lm = lane & 15, lq = lane >> 4;
    const int mh = wv >> 2, nq2 = wv & 3;       // S^T split: m-half x n-quarter
    const int nq = wv >> 2, cq = wv & 3;        // PV split: n-half x c-quarter

    // Hoisted S^T B-frags: xc for wave's 2 n-tiles (nq2*2, nq2*2+1)
    short8 cB2[2][2][2];   // [ntile][kc][hilo]
#pragma unroll
    for (int ntile = 0; ntile < 2; ++ntile) {
        const int gt = nblk * 8 + nq2 * 2 + ntile;
        const size_t base = ((size_t)(b * 256 + gt) * 2) * 64 + lane;
        cB2[ntile][0][0] = xcPh[base];
        cB2[ntile][1][0] = xcPh[base + 64];
        cB2[ntile][0][1] = xcPl[base];
        cB2[ntile][1][1] = xcPl[base + 64];
    }
    asm volatile("s_waitcnt vmcnt(0)" ::: "memory");   // clean slate for counts

    auto stage = [&](int smt, int bufi) {
        short8* XT = XTs + bufi * 1024;
        short8* XB = XBs + bufi * 2048;
        const size_t abase = ((size_t)(b * 512 + smt * 8)) * 64;
#pragma unroll
        for (int k = 0; k < 2; ++k) {            // 2 xt chunks (issued FIRST)
            const int c = wv * 2 + k, ms = c >> 2, part = c & 3;
            const short8* src = (part < 2 ? xtPh : xtPl)
                                + abase + ms * 128 + (part & 1) * 64 + lane;
            GLL16(src, XT + c * 64);
        }
        const size_t p8 = ((size_t)(b * 2048 + smt * 32)) * 64;
#pragma unroll
        for (int k = 0; k < 4; ++k) {            // 4 xb chunks
            const int e = k * 512 + wv * 64;
            GLL16(xbP + p8 + e + lane, XB + e);
        }
    };
    stage(0, 0);                                 // prologue: 6 loads in flight

    f32x4 acc[4][4];   // O partial [n-subtile within half][c-tile within quarter]
#pragma unroll
    for (int i = 0; i < 4; ++i)
#pragma unroll
        for (int jj = 0; jj < 4; ++jj) acc[i][jj] = f32x4{0.f, 0.f, 0.f, 0.f};
    float zp = 0.f;

    for (int mt = 0; mt < 64; ++mt) {
        const int cur = mt & 1;
        // own cur-xt (oldest 2 of 6) landed; cur-xb still in flight
        asm volatile("s_waitcnt vmcnt(4)" ::: "memory");
        __builtin_amdgcn_sched_barrier(0);
        __builtin_amdgcn_s_barrier();            // all waves' xt staged; all
        __builtin_amdgcn_sched_barrier(0);       // finished prev PV reads
        // issue next tile's 6 loads into the other buffer (wrap keeps counts
        // uniform; final wrap-stage is harmless)
        stage((mt + 1) & 63, cur ^ 1);

        // ---- S^T: wave = (mh, nq2) -> 32 m x 32 n of this mt's 64x128 ----
        const short8* XT = XTs + cur * 1024;
#pragma unroll
        for (int ms2 = 0; ms2 < 2; ++ms2) {
            const int ms = mh * 2 + ms2;
            const short8 aH0 = XT[(ms * 4 + 0) * 64 + lane];
            const short8 aH1 = XT[(ms * 4 + 1) * 64 + lane];
            const short8 aL0 = XT[(ms * 4 + 2) * 64 + lane];
            const short8 aL1 = XT[(ms * 4 + 3) * 64 + lane];
#pragma unroll
            for (int ntile = 0; ntile < 2; ++ntile) {
                f32x4 s = {0.f, 0.f, 0.f, 0.f};
                __builtin_amdgcn_s_setprio(1);
                s = __builtin_amdgcn_mfma_f32_16x16x32_bf16(aH0, cB2[ntile][0][0], s, 0, 0, 0);
                s = __builtin_amdgcn_mfma_f32_16x16x32_bf16(aH1, cB2[ntile][1][0], s, 0, 0, 0);
                s = __builtin_amdgcn_mfma_f32_16x16x32_bf16(aH0, cB2[ntile][0][1], s, 0, 0, 0);
                s = __builtin_amdgcn_mfma_f32_16x16x32_bf16(aH1, cB2[ntile][1][1], s, 0, 0, 0);
                s = __builtin_amdgcn_mfma_f32_16x16x32_bf16(aL0, cB2[ntile][0][0], s, 0, 0, 0);
                s = __builtin_amdgcn_mfma_f32_16x16x32_bf16(aL1, cB2[ntile][1][0], s, 0, 0, 0);
                __builtin_amdgcn_s_setprio(0);
                const float e0 = __expf(s[0]), e1 = __expf(s[1]);
                const float e2 = __expf(s[2]), e3 = __expf(s[3]);
                zp += (e0 + e1) + (e2 + e3);
                short4v pk = { bfbits(e0), bfbits(e1), bfbits(e2), bfbits(e3) };
                // n = T*16+lm, m = ms*16+lq*4  ->  [T][mh][lqp*16+lm] + (lq&1)*8B
                const int T = nq2 * 2 + ntile;
                const int lqp = (ms & 1) * 2 + (lq >> 1);
                Ps4[(((T * 2 + mh) * 64) + lqp * 16 + lm) * 2 + (lq & 1)] = pk;
            }
        }
        // cur-xb (oldest 4 of 10) landed; next tile's 6 stay in flight.
        // lgkmcnt(0): own Ps writes visible before signaling.
        asm volatile("s_waitcnt vmcnt(6) lgkmcnt(0)" ::: "memory");
        __builtin_amdgcn_sched_barrier(0);
        __builtin_amdgcn_s_barrier();            // XB[cur] + all Ps visible
        __builtin_amdgcn_sched_barrier(0);

        // ---- PV: wave = (nq, cq) -> 64 n x 64 c, conflict-free frag reads ----
        const short8* XB = XBs + cur * 2048;
        short8 vb0[4], vb1[4];
#pragma unroll
        for (int q4 = 0; q4 < 4; ++q4) {
            const int ct = cq * 4 + q4;
            vb0[q4] = XB[ct * 64 + lane];
            vb1[q4] = XB[1024 + ct * 64 + lane];
        }
#pragma unroll
        for (int nt2 = 0; nt2 < 4; ++nt2) {
            const int T = nq * 4 + nt2;
            const short8 pa0 = Ps8[(T * 2 + 0) * 64 + lane];
            const short8 pa1 = Ps8[(T * 2 + 1) * 64 + lane];
            __builtin_amdgcn_s_setprio(1);
#pragma unroll
            for (int q4 = 0; q4 < 4; ++q4) {
                acc[nt2][q4] = __builtin_amdgcn_mfma_f32_16x16x32_bf16(
                    pa0, vb0[q4], acc[nt2][q4], 0, 0, 0);
                acc[nt2][q4] = __builtin_amdgcn_mfma_f32_16x16x32_bf16(
                    pa1, vb1[q4], acc[nt2][q4], 0, 0, 0);
            }
            __builtin_amdgcn_s_setprio(0);
        }
    }

    // Z: block reduction -> one atomicAdd
#pragma unroll
    for (int o = 32; o > 0; o >>= 1) zp += __shfl_down(zp, o, 64);
    if (lane == 0) zred[wv] = zp;
    __syncthreads();
    if (t == 0) {
        float zs = 0.f;
#pragma unroll
        for (int wvi = 0; wvi < 8; ++wvi) zs += zred[wvi];
        atomicAdd(&Z[b], zs);
    }

    // O direct stores (sole writer of this (b, n-stripe))
#pragma unroll
    for (int nt2 = 0; nt2 < 4; ++nt2) {
#pragma unroll
        for (int q4 = 0; q4 < 4; ++q4) {
            const int c = cq * 64 + q4 * 16 + lm;
#pragma unroll
            for (int r = 0; r < 4; ++r) {
                const int n = n0 + (nq * 4 + nt2) * 16 + lq * 4 + r;
                O[((size_t)b * HW_ + n) * C_ + c] = acc[nt2][q4][r];
            }
        }
    }
}

// ---------------------------------------------------------------------------
// K4: y = x + O*(1/Z[b]) (flat reinterpretation add).
// ---------------------------------------------------------------------------
__global__ __launch_bounds__(256) void k_add(
    const float* __restrict__ x, const float* __restrict__ o,
    const float* __restrict__ Z, float* __restrict__ y)
{
    const int bidx = blockIdx.x;
    const float invZ = 1.0f / Z[bidx >> 10];
    const size_t i = ((size_t)bidx * 256 + threadIdx.x) * 4;
    const float4 a = *reinterpret_cast<const float4*>(&x[i]);
    const float4 b = *reinterpret_cast<const float4*>(&o[i]);
    float4 r{fmaf(b.x, invZ, a.x), fmaf(b.y, invZ, a.y),
             fmaf(b.z, invZ, a.z), fmaf(b.w, invZ, a.w)};
    *reinterpret_cast<float4*>(&y[i]) = r;
}

extern "C" void kernel_launch(void* const* d_in, const int* in_sizes, int n_in,
                              void* d_out, int out_size, void* d_ws, size_t ws_size,
                              hipStream_t stream)
{
    const float* x   = (const float*)d_in[0];
    const float* wt  = (const float*)d_in[1];
    const float* bt  = (const float*)d_in[2];
    const float* wc  = (const float*)d_in[3];
    const float* bc  = (const float*)d_in[4];
    const float* wbo = (const float*)d_in[5];
    const float* bbo = (const float*)d_in[6];
    const float* wo  = (const float*)d_in[7];
    const float* bo  = (const float*)d_in[8];
    float* out = (float*)d_out;

    uint8_t* w8 = (uint8_t*)d_ws;
    const size_t MB = 1u << 20;
    short8* xtPh = (short8*)(w8);
    short8* xtPl = (short8*)(w8 + 4 * MB);
    short8* xcPh = (short8*)(w8 + 8 * MB);
    short8* xcPl = (short8*)(w8 + 12 * MB);
    __hip_bfloat16* xbB = (__hip_bfloat16*)(w8 + 16 * MB);
    short8* xbP  = (short8*)(w8 + 32 * MB);
    float*  O    = (float*)(w8 + 48 * MB);
    short8* Wb1  = (short8*)(w8 + 48 * MB);   // inside O region (dead before attn)
    short8* Wb2  = (short8*)(w8 + 32 * MB);   // inside xbP region (dead after attn)
    float*  y    = (float*)(w8);              // [0,32) after attn
    float*  Z    = (float*)(w8 + 80 * MB);

    hipMemsetAsync(Z, 0, B_ * sizeof(float), stream);
    k_prep_w<<<dim3(288), 256, 0, stream>>>(wbo, Wb1);
    k_conv1x1<<<dim3(16, 8, 8), 256, 0, stream>>>(x, wt, bt, wc, bc,
                                                  xtPh, xtPl, xcPh, xcPl);
    k_conv3x3_mfma<__hip_bfloat16><<<dim3(64, 2, 8), 256, 0, stream>>>(x, Wb1, bbo, xbB);
    k_pack_xb<<<dim3(4096), 256, 0, stream>>>(xbB, xbP);
    k_attn_mfma<<<dim3(256), dim3(512), 114720, stream>>>(xtPh, xtPl, xcPh, xcPl,
                                                          xbP, O, Z);
    k_prep_w<<<dim3(288), 256, 0, stream>>>(wo, Wb2);
    k_add<<<dim3(8192), 256, 0, stream>>>(x, O, Z, y);
    k_conv3x3_mfma<float><<<dim3(64, 2, 8), 256, 0, stream>>>(y, Wb2, bo, out);
}

// Round 4
// 386.662 us; speedup vs baseline: 2.5656x; 1.0343x over previous
//
#include <hip/hip_runtime.h>
#include <hip/hip_bf16.h>
#include <type_traits>

constexpr int B_ = 8, C_ = 256, P_ = 64, H_ = 64, W_ = 64, HW_ = 4096;

typedef __attribute__((ext_vector_type(8))) short short8;   // 8 bf16
typedef __attribute__((ext_vector_type(4))) short short4v;  // 4 bf16 (8 B)
typedef __attribute__((ext_vector_type(4))) float f32x4;

__device__ __forceinline__ short bfbits(float f) {
    __hip_bfloat16 h = __float2bfloat16(f);
    return *reinterpret_cast<short*>(&h);
}
__device__ __forceinline__ float bf2f(short s) {
    __hip_bfloat16 h = *reinterpret_cast<__hip_bfloat16*>(&s);
    return (float)h;
}

// async global->LDS, 16B per lane; dst must be wave-uniform base (HW adds lane*16)
#define GLL16(gsrc, ldst)                                                      \
    __builtin_amdgcn_global_load_lds(                                         \
        (const __attribute__((address_space(1))) void*)(gsrc),                \
        (__attribute__((address_space(3))) void*)(ldst), 16, 0, 0)

// ---------------------------------------------------------------------------
// Fragment-linear packed layouts (one wave-load = base + lane*16, contiguous):
//   xtP/xcP [b][tile16][kc2][lane64]x16B : chunk = x[row=tile*16+lm][p=kc*32+lq*8..+8]
//   xbP     [b][g128][ct16][lane64]x16B  : chunk = xb[c=ct*16+lm][m=g*32+lq*8..+8]
//   wbP     [tap9][cb8][cot16][lane64]x16B: chunk = w[co=cot*16+lm][ci=cb*32+lq*8..+8]
// ---------------------------------------------------------------------------

// K0: weight prep, fp32 OIHW -> fragment-linear bf16 wbP. 288 blocks.
__global__ __launch_bounds__(256) void k_prep_w(
    const float* __restrict__ w, short8* __restrict__ wbP)
{
    const int idx = blockIdx.x * 256 + threadIdx.x;      // < 9*8*16*64 = 73728
    const int lane = idx & 63, cot = (idx >> 6) & 15;
    const int cb = (idx >> 10) & 7, tap = idx >> 13;
    const int lm = lane & 15, lq = lane >> 4;
    const int co = cot * 16 + lm, ci0 = cb * 32 + lq * 8;
    short8 v;
#pragma unroll
    for (int k = 0; k < 8; ++k)
        v[k] = bfbits(w[(co * 256 + ci0 + k) * 9 + tap]);
    wbP[idx] = v;
}

// K0b: xb [B][C][HW] bf16 -> fragment-linear xbP. 4096 blocks.
__global__ __launch_bounds__(256) void k_pack_xb(
    const __hip_bfloat16* __restrict__ xb, short8* __restrict__ xbP)
{
    const int tid = blockIdx.x * 256 + threadIdx.x;
    const int lane = tid & 63, wid = tid >> 6;           // wid < 8*128*16
    const int ct = wid & 15, g = (wid >> 4) & 127, b = wid >> 11;
    const int c = ct * 16 + (lane >> 2);
    const int mo = g * 32 + (lane & 3) * 8;
    const short8 v = *reinterpret_cast<const short8*>(
        &xb[((size_t)(b * 256 + c)) * HW_ + mo]);
    xbP[(size_t)wid * 64 + (lane & 3) * 16 + (lane >> 2)] = v;
}

// ---------------------------------------------------------------------------
// K1: 1x1 convs, p-quarter split (grid 16x8x8). Epilogue writes hi/lo bf16
// directly in fragment-linear xtP/xcP order.
// ---------------------------------------------------------------------------
__global__ __launch_bounds__(256) void k_conv1x1(
    const float* __restrict__ x,
    const float* __restrict__ w_top, const float* __restrict__ b_top,
    const float* __restrict__ w_cen, const float* __restrict__ b_cen,
    short8* __restrict__ xtPh, short8* __restrict__ xtPl,
    short8* __restrict__ xcPh, short8* __restrict__ xcPl)
{
    const int b = blockIdx.z;
    const int n = blockIdx.x * 256 + threadIdx.x;
    const int conv = blockIdx.y >> 2, pq = blockIdx.y & 3;
    const int p0 = pq * 16;
    const float* w    = conv ? w_cen : w_top;
    const float* bias = conv ? b_cen : b_top;
    short8* oh = conv ? xcPh : xtPh;
    short8* ol = conv ? xcPl : xtPl;

    const float* xp = x + (size_t)b * C_ * HW_ + n;
    float acc[16];
#pragma unroll
    for (int p = 0; p < 16; ++p) acc[p] = 0.f;

    for (int c = 0; c < C_; c += 4) {
        const float xv0 = xp[(size_t)(c + 0) * HW_];
        const float xv1 = xp[(size_t)(c + 1) * HW_];
        const float xv2 = xp[(size_t)(c + 2) * HW_];
        const float xv3 = xp[(size_t)(c + 3) * HW_];
#pragma unroll
        for (int p = 0; p < 16; ++p) {
            const float4 wv = *reinterpret_cast<const float4*>(&w[(p0 + p) * C_ + c]);
            float a = acc[p];
            a = fmaf(wv.x, xv0, a);
            a = fmaf(wv.y, xv1, a);
            a = fmaf(wv.z, xv2, a);
            a = fmaf(wv.w, xv3, a);
            acc[p] = a;
        }
    }
    const int nt = n >> 4, lmn = n & 15;
    const size_t obase = ((size_t)(b * 256 + nt) * 2 + (pq >> 1)) * 64 + lmn;
#pragma unroll
    for (int jj = 0; jj < 2; ++jj) {
        short8 vh, vl;
#pragma unroll
        for (int k = 0; k < 8; ++k) {
            const float v = acc[jj * 8 + k] + bias[p0 + jj * 8 + k];
            const short hb = bfbits(v);
            vh[k] = hb;
            vl[k] = bfbits(v - bf2f(hb));   // residual for hi/lo split
        }
        const size_t idx = obase + (size_t)(((pq & 1) * 2 + jj) * 16);
        oh[idx] = vh;
        ol[idx] = vl;
    }
}

// ---------------------------------------------------------------------------
// K2/K5: 3x3 conv as implicit GEMM, bf16 MFMA. R11: merged co-halves — one
// 512-thread/8-wave block computes ALL 256 co for one h-row (x staged ONCE,
// was twice), grid 512 1D with b==XCD (4MB x-slab + 1.2MB weights L2-pinned).
// Staging decode flipped to lane->w (coalesced 256B segments, was 32-row
// gather). acc only 32 regs -> __launch_bounds__(512,4) = 2 blocks/CU =
// 4 waves/SIMD to hide the in-loop L2 weight-fragment latency; tap loop
// unroll 3 pipelines the af loads.
// ---------------------------------------------------------------------------
template <typename OT>
__global__ __launch_bounds__(512, 4) void k_conv3x3_mfma(
    const float* __restrict__ xin, const short8* __restrict__ wbP,
    const float* __restrict__ bias, OT* __restrict__ out)
{
    __shared__ __align__(16) __hip_bfloat16 Xs[3][66][40];
    const int lin = blockIdx.x;                 // 0..511
    const int b = lin & 7, h = lin >> 3;        // b == XCD
    const int t = threadIdx.x;
    const int wave = t >> 6, lane = t & 63;
    const int lm = lane & 15, lq = lane >> 4;
    const int cobase = wave * 32;
    const int cot0 = wave * 2;                  // co-tile index base (co/16)

    f32x4 acc[4][2];   // [n_tile][co_tile]
#pragma unroll
    for (int i = 0; i < 4; ++i)
#pragma unroll
        for (int j = 0; j < 2; ++j) acc[i][j] = f32x4{0.f, 0.f, 0.f, 0.f};

    if (t < 192) {   // zero w-halo columns once (3 r x 2 sides x 32 ci)
        const int r = t >> 6, cc = t & 31, side = (t >> 5) & 1;
        Xs[r][side ? 65 : 0][cc] = __float2bfloat16(0.f);
    }

    const float* xbase = xin + (size_t)b * C_ * HW_;

    for (int cb = 0; cb < 8; ++cb) {
        const int ci0 = cb * 32;
        __syncthreads();
        // stage 3 rows x 32 ci x 64 w: 1536 float4 over 512 threads.
        // idx -> (r, ci, wq); lanes 0..15 share ci, consecutive wq -> 256B
        // coalesced global segments.
#pragma unroll
        for (int it = 0; it < 3; ++it) {
            const int idx = it * 512 + t;
            const int r = idx >> 9, ci = (idx >> 4) & 31, wq = idx & 15;
            const int hh = h + r - 1;
            float4 v = {0.f, 0.f, 0.f, 0.f};
            if (hh >= 0 && hh < H_)
                v = *reinterpret_cast<const float4*>(
                    &xbase[(size_t)(ci0 + ci) * HW_ + hh * W_ + wq * 4]);
            Xs[r][1 + wq * 4 + 0][ci] = __float2bfloat16(v.x);
            Xs[r][1 + wq * 4 + 1][ci] = __float2bfloat16(v.y);
            Xs[r][1 + wq * 4 + 2][ci] = __float2bfloat16(v.z);
            Xs[r][1 + wq * 4 + 3][ci] = __float2bfloat16(v.w);
        }
        __syncthreads();

#pragma unroll 3
        for (int tap = 0; tap < 9; ++tap) {
            const int dh = tap / 3;
            const int dw = tap % 3;
            const short8* wp = wbP + ((size_t)(tap * 8 + cb)) * 1024 + lane;
            short8 af[2];
            af[0] = wp[(cot0 + 0) * 64];
            af[1] = wp[(cot0 + 1) * 64];
            short8 bf[4];
#pragma unroll
            for (int nt = 0; nt < 4; ++nt)
                bf[nt] = *reinterpret_cast<const short8*>(
                    &Xs[dh][nt * 16 + lm + dw][lq * 8]);
#pragma unroll
            for (int nt = 0; nt < 4; ++nt)
#pragma unroll
                for (int ct = 0; ct < 2; ++ct)
                    acc[nt][ct] = __builtin_amdgcn_mfma_f32_16x16x32_bf16(
                        af[ct], bf[nt], acc[nt][ct], 0, 0, 0);
        }
    }

#pragma unroll
    for (int nt = 0; nt < 4; ++nt) {
        const int pos = h * W_ + nt * 16 + lm;
#pragma unroll
        for (int ct = 0; ct < 2; ++ct) {
            const int co = cobase + ct * 16 + lq * 4;
#pragma unroll
            for (int r = 0; r < 4; ++r) {
                const float v = acc[nt][ct][r] + bias[co + r];
                if constexpr (std::is_same<OT, __hip_bfloat16>::value)
                    out[((size_t)(b * C_ + co + r)) * HW_ + pos] = __float2bfloat16(v);
                else
                    out[((size_t)(b * C_ + co + r)) * HW_ + pos] = v;
            }
        }
    }
}

// ---------------------------------------------------------------------------
// K3: fused attention. R10 structure (unchanged): one block per (b, 128-n
// stripe), grid 256, all 64 mt per block, double-buffered XT/XB via
// global_load_lds with counted vmcnt, S^T 2m x 4n wave split, fragment-
// linear Ps. 2 barriers/iter. LDS 114.7 KB, 1 block/CU. b == XCD.
// ---------------------------------------------------------------------------
__global__ __launch_bounds__(512, 2) void k_attn_mfma(
    const short8* __restrict__ xtPh, const short8* __restrict__ xtPl,
    const short8* __restrict__ xcPh, const short8* __restrict__ xcPl,
    const short8* __restrict__ xbP, float* __restrict__ O,
    float* __restrict__ Z)
{
    extern __shared__ __align__(16) char smem[];
    short8* XTs = (short8*)smem;                    // [2][1024]  (2 x 16 KB)
    short8* XBs = (short8*)(smem + 32768);          // [2][2048]  (2 x 32 KB)
    short8* Ps8 = (short8*)(smem + 98304);          // [8 T][2 mh][64]  16 KB
    short4v* Ps4 = (short4v*)(smem + 98304);
    float* zred = (float*)(smem + 114688);

    const int lin = blockIdx.x;                 // 0..255
    const int b = lin & 7, nblk = lin >> 3;     // b == XCD (round-robin dispatch)
    const int n0 = nblk * 128;

    const int t = threadIdx.x, wv = t >> 6, lane = t & 63;
    const int lm = lane & 15, lq = lane >> 4;
    const int mh = wv >> 2, nq2 = wv & 3;       // S^T split: m-half x n-quarter
    const int nq = wv >> 2, cq = wv & 3;        // PV split: n-half x c-quarter

    // Hoisted S^T B-frags: xc for wave's 2 n-tiles (nq2*2, nq2*2+1)
    short8 cB2[2][2][2];   // [ntile][kc][hilo]
#pragma unroll
    for (int ntile = 0; ntile < 2; ++ntile) {
        const int gt = nblk * 8 + nq2 * 2 + ntile;
        const size_t base = ((size_t)(b * 256 + gt) * 2) * 64 + lane;
        cB2[ntile][0][0] = xcPh[base];
        cB2[ntile][1][0] = xcPh[base + 64];
        cB2[ntile][0][1] = xcPl[base];
        cB2[ntile][1][1] = xcPl[base + 64];
    }
    asm volatile("s_waitcnt vmcnt(0)" ::: "memory");   // clean slate for counts

    auto stage = [&](int smt, int bufi) {
        short8* XT = XTs + bufi * 1024;
        short8* XB = XBs + bufi * 2048;
        const size_t abase = ((size_t)(b * 512 + smt * 8)) * 64;
#pragma unroll
        for (int k = 0; k < 2; ++k) {            // 2 xt chunks (issued FIRST)
            const int c = wv * 2 + k, ms = c >> 2, part = c & 3;
            const short8* src = (part < 2 ? xtPh : xtPl)
                                + abase + ms * 128 + (part & 1) * 64 + lane;
            GLL16(src, XT + c * 64);
        }
        const size_t p8 = ((size_t)(b * 2048 + smt * 32)) * 64;
#pragma unroll
        for (int k = 0; k < 4; ++k) {            // 4 xb chunks
            const int e = k * 512 + wv * 64;
            GLL16(xbP + p8 + e + lane, XB + e);
        }
    };
    stage(0, 0);                                 // prologue: 6 loads in flight

    f32x4 acc[4][4];   // O partial [n-subtile within half][c-tile within quarter]
#pragma unroll
    for (int i = 0; i < 4; ++i)
#pragma unroll
        for (int jj = 0; jj < 4; ++jj) acc[i][jj] = f32x4{0.f, 0.f, 0.f, 0.f};
    float zp = 0.f;

    for (int mt = 0; mt < 64; ++mt) {
        const int cur = mt & 1;
        // own cur-xt (oldest 2 of 6) landed; cur-xb still in flight
        asm volatile("s_waitcnt vmcnt(4)" ::: "memory");
        __builtin_amdgcn_sched_barrier(0);
        __builtin_amdgcn_s_barrier();            // all waves' xt staged; all
        __builtin_amdgcn_sched_barrier(0);       // finished prev PV reads
        // issue next tile's 6 loads into the other buffer (wrap keeps counts
        // uniform; final wrap-stage is harmless)
        stage((mt + 1) & 63, cur ^ 1);

        // ---- S^T: wave = (mh, nq2) -> 32 m x 32 n of this mt's 64x128 ----
        const short8* XT = XTs + cur * 1024;
#pragma unroll
        for (int ms2 = 0; ms2 < 2; ++ms2) {
            const int ms = mh * 2 + ms2;
            const short8 aH0 = XT[(ms * 4 + 0) * 64 + lane];
            const short8 aH1 = XT[(ms * 4 + 1) * 64 + lane];
            const short8 aL0 = XT[(ms * 4 + 2) * 64 + lane];
            const short8 aL1 = XT[(ms * 4 + 3) * 64 + lane];
#pragma unroll
            for (int ntile = 0; ntile < 2; ++ntile) {
                f32x4 s = {0.f, 0.f, 0.f, 0.f};
                __builtin_amdgcn_s_setprio(1);
                s = __builtin_amdgcn_mfma_f32_16x16x32_bf16(aH0, cB2[ntile][0][0], s, 0, 0, 0);
                s = __builtin_amdgcn_mfma_f32_16x16x32_bf16(aH1, cB2[ntile][1][0], s, 0, 0, 0);
                s = __builtin_amdgcn_mfma_f32_16x16x32_bf16(aH0, cB2[ntile][0][1], s, 0, 0, 0);
                s = __builtin_amdgcn_mfma_f32_16x16x32_bf16(aH1, cB2[ntile][1][1], s, 0, 0, 0);
                s = __builtin_amdgcn_mfma_f32_16x16x32_bf16(aL0, cB2[ntile][0][0], s, 0, 0, 0);
                s = __builtin_amdgcn_mfma_f32_16x16x32_bf16(aL1, cB2[ntile][1][0], s, 0, 0, 0);
                __builtin_amdgcn_s_setprio(0);
                const float e0 = __expf(s[0]), e1 = __expf(s[1]);
                const float e2 = __expf(s[2]), e3 = __expf(s[3]);
                zp += (e0 + e1) + (e2 + e3);
                short4v pk = { bfbits(e0), bfbits(e1), bfbits(e2), bfbits(e3) };
                // n = T*16+lm, m = ms*16+lq*4  ->  [T][mh][lqp*16+lm] + (lq&1)*8B
                const int T = nq2 * 2 + ntile;
                const int lqp = (ms & 1) * 2 + (lq >> 1);
                Ps4[(((T * 2 + mh) * 64) + lqp * 16 + lm) * 2 + (lq & 1)] = pk;
            }
        }
        // cur-xb (oldest 4 of 10) landed; next tile's 6 stay in flight.
        // lgkmcnt(0): own Ps writes visible before signaling.
        asm volatile("s_waitcnt vmcnt(6) lgkmcnt(0)" ::: "memory");
        __builtin_amdgcn_sched_barrier(0);
        __builtin_amdgcn_s_barrier();            // XB[cur] + all Ps visible
        __builtin_amdgcn_sched_barrier(0);

        // ---- PV: wave = (nq, cq) -> 64 n x 64 c, conflict-free frag reads ----
        const short8* XB = XBs + cur * 2048;
        short8 vb0[4], vb1[4];
#pragma unroll
        for (int q4 = 0; q4 < 4; ++q4) {
            const int ct = cq * 4 + q4;
            vb0[q4] = XB[ct * 64 + lane];
            vb1[q4] = XB[1024 + ct * 64 + lane];
        }
#pragma unroll
        for (int nt2 = 0; nt2 < 4; ++nt2) {
            const int T = nq * 4 + nt2;
            const short8 pa0 = Ps8[(T * 2 + 0) * 64 + lane];
            const short8 pa1 = Ps8[(T * 2 + 1) * 64 + lane];
            __builtin_amdgcn_s_setprio(1);
#pragma unroll
            for (int q4 = 0; q4 < 4; ++q4) {
                acc[nt2][q4] = __builtin_amdgcn_mfma_f32_16x16x32_bf16(
                    pa0, vb0[q4], acc[nt2][q4], 0, 0, 0);
                acc[nt2][q4] = __builtin_amdgcn_mfma_f32_16x16x32_bf16(
                    pa1, vb1[q4], acc[nt2][q4], 0, 0, 0);
            }
            __builtin_amdgcn_s_setprio(0);
        }
    }

    // Z: block reduction -> one atomicAdd
#pragma unroll
    for (int o = 32; o > 0; o >>= 1) zp += __shfl_down(zp, o, 64);
    if (lane == 0) zred[wv] = zp;
    __syncthreads();
    if (t == 0) {
        float zs = 0.f;
#pragma unroll
        for (int wvi = 0; wvi < 8; ++wvi) zs += zred[wvi];
        atomicAdd(&Z[b], zs);
    }

    // O direct stores (sole writer of this (b, n-stripe))
#pragma unroll
    for (int nt2 = 0; nt2 < 4; ++nt2) {
#pragma unroll
        for (int q4 = 0; q4 < 4; ++q4) {
            const int c = cq * 64 + q4 * 16 + lm;
#pragma unroll
            for (int r = 0; r < 4; ++r) {
                const int n = n0 + (nq * 4 + nt2) * 16 + lq * 4 + r;
                O[((size_t)b * HW_ + n) * C_ + c] = acc[nt2][q4][r];
            }
        }
    }
}

// ---------------------------------------------------------------------------
// K4: y = x + O*(1/Z[b]) (flat reinterpretation add).
// ---------------------------------------------------------------------------
__global__ __launch_bounds__(256) void k_add(
    const float* __restrict__ x, const float* __restrict__ o,
    const float* __restrict__ Z, float* __restrict__ y)
{
    const int bidx = blockIdx.x;
    const float invZ = 1.0f / Z[bidx >> 10];
    const size_t i = ((size_t)bidx * 256 + threadIdx.x) * 4;
    const float4 a = *reinterpret_cast<const float4*>(&x[i]);
    const float4 b = *reinterpret_cast<const float4*>(&o[i]);
    float4 r{fmaf(b.x, invZ, a.x), fmaf(b.y, invZ, a.y),
             fmaf(b.z, invZ, a.z), fmaf(b.w, invZ, a.w)};
    *reinterpret_cast<float4*>(&y[i]) = r;
}

extern "C" void kernel_launch(void* const* d_in, const int* in_sizes, int n_in,
                              void* d_out, int out_size, void* d_ws, size_t ws_size,
                              hipStream_t stream)
{
    const float* x   = (const float*)d_in[0];
    const float* wt  = (const float*)d_in[1];
    const float* bt  = (const float*)d_in[2];
    const float* wc  = (const float*)d_in[3];
    const float* bc  = (const float*)d_in[4];
    const float* wbo = (const float*)d_in[5];
    const float* bbo = (const float*)d_in[6];
    const float* wo  = (const float*)d_in[7];
    const float* bo  = (const float*)d_in[8];
    float* out = (float*)d_out;

    uint8_t* w8 = (uint8_t*)d_ws;
    const size_t MB = 1u << 20;
    short8* xtPh = (short8*)(w8);
    short8* xtPl = (short8*)(w8 + 4 * MB);
    short8* xcPh = (short8*)(w8 + 8 * MB);
    short8* xcPl = (short8*)(w8 + 12 * MB);
    __hip_bfloat16* xbB = (__hip_bfloat16*)(w8 + 16 * MB);
    short8* xbP  = (short8*)(w8 + 32 * MB);
    float*  O    = (float*)(w8 + 48 * MB);
    short8* Wb1  = (short8*)(w8 + 48 * MB);   // inside O region (dead before attn)
    short8* Wb2  = (short8*)(w8 + 32 * MB);   // inside xbP region (dead after attn)
    float*  y    = (float*)(w8);              // [0,32) after attn
    float*  Z    = (float*)(w8 + 80 * MB);

    hipMemsetAsync(Z, 0, B_ * sizeof(float), stream);
    k_prep_w<<<dim3(288), 256, 0, stream>>>(wbo, Wb1);
    k_conv1x1<<<dim3(16, 8, 8), 256, 0, stream>>>(x, wt, bt, wc, bc,
                                                  xtPh, xtPl, xcPh, xcPl);
    k_conv3x3_mfma<__hip_bfloat16><<<dim3(512), 512, 0, stream>>>(x, Wb1, bbo, xbB);
    k_pack_xb<<<dim3(4096), 256, 0, stream>>>(xbB, xbP);
    k_attn_mfma<<<dim3(256), dim3(512), 114720, stream>>>(xtPh, xtPl, xcPh, xcPl,
                                                          xbP, O, Z);
    k_prep_w<<<dim3(288), 256, 0, stream>>>(wo, Wb2);
    k_add<<<dim3(8192), 256, 0, stream>>>(x, O, Z, y);
    k_conv3x3_mfma<float><<<dim3(512), 512, 0, stream>>>(y, Wb2, bo, out);
}